// Round 5
// baseline (2213.666 us; speedup 1.0000x reference)
//
#include <hip/hip_runtime.h>

typedef unsigned short u16;
typedef unsigned int   u32;

// ---------------------------------------------------------------------------
// K1: h = x @ W^T (fp32), fused al/ar.
// Block = 128 threads (thread = column c), handles 8 nodes; x staged in LDS.
// ---------------------------------------------------------------------------
__global__ __launch_bounds__(128) void node_h(
        const float* __restrict__ x, const float* __restrict__ W,
        const float* __restrict__ att,
        float* __restrict__ h, float* __restrict__ al, float* __restrict__ ar,
        int n) {
    __shared__ float xs[8][128];
    const int c  = threadIdx.x;
    const int nb = blockIdx.x * 8;

    for (int i = c; i < 8 * 128; i += 128) {
        int node = nb + (i >> 7);
        xs[i >> 7][i & 127] = (node < n) ? x[(size_t)node * 128 + (i & 127)] : 0.f;
    }
    __syncthreads();

    float acc[8];
#pragma unroll
    for (int i = 0; i < 8; ++i) acc[i] = 0.f;

#pragma unroll 4
    for (int k = 0; k < 128; ++k) {
        float w = W[c * 128 + k];
#pragma unroll
        for (int i = 0; i < 8; ++i) acc[i] = fmaf(xs[i][k], w, acc[i]);
    }

#pragma unroll
    for (int i = 0; i < 8; ++i) {
        int node = nb + i;
        if (node < n) h[(size_t)node * 128 + c] = acc[i];
    }

    // al/ar: head = c>>4, d = c&15; reduce over the 16 lanes of a head
    const int head = c >> 4;
    const int d    = c & 15;
    const float atl = att[head * 32 + d];
    const float atr = att[head * 32 + 16 + d];
#pragma unroll
    for (int i = 0; i < 8; ++i) {
        float pl = acc[i] * atl;
        float pr = acc[i] * atr;
#pragma unroll
        for (int off = 1; off < 16; off <<= 1) {
            pl += __shfl_xor(pl, off, 64);
            pr += __shfl_xor(pr, off, 64);
        }
        int node = nb + i;
        if (d == 0 && node < n) {
            al[node * 8 + head] = pl;
            ar[node * 8 + head] = pr;
        }
    }
}

// ---------------------------------------------------------------------------
// K2: one thread per edge: rowsum[row][h] += exp(leaky(al+ar)) * pos[col]
// ---------------------------------------------------------------------------
__global__ __launch_bounds__(256) void edge_rowsum(
        const int* __restrict__ ei, const float* __restrict__ pos,
        const float* __restrict__ al, const float* __restrict__ ar,
        float* __restrict__ rowsum, int E) {
    int e = blockIdx.x * 256 + threadIdx.x;
    if (e >= E) return;
    int r = ei[e];
    int c = ei[E + e];
    float p = pos[c];
    float4 l0 = *(const float4*)&al[r * 8];
    float4 l1 = *(const float4*)&al[r * 8 + 4];
    float4 r0 = *(const float4*)&ar[c * 8];
    float4 r1 = *(const float4*)&ar[c * 8 + 4];
    float a[8] = {l0.x + r0.x, l0.y + r0.y, l0.z + r0.z, l0.w + r0.w,
                  l1.x + r1.x, l1.y + r1.y, l1.z + r1.z, l1.w + r1.w};
#pragma unroll
    for (int hh = 0; hh < 8; ++hh) {
        float v = a[hh];
        v = (v >= 0.f) ? v : 0.2f * v;
        v = __expf(v) * p;
        unsafeAtomicAdd(&rowsum[r * 8 + hh], v);
    }
}

// ---------------------------------------------------------------------------
// K3: wave per edge: lanes 0-7 compute head alphas, broadcast via shfl,
// lane l scatters cols 2l,2l+1: accum[row][col] += alpha * h[col_node][col]
// ---------------------------------------------------------------------------
__global__ __launch_bounds__(256) void edge_scatter(
        const int* __restrict__ ei, const float* __restrict__ pos,
        const float* __restrict__ al, const float* __restrict__ ar,
        const float* __restrict__ h, float* __restrict__ accum, int E) {
    int wid  = (blockIdx.x * 256 + threadIdx.x) >> 6;
    int lane = threadIdx.x & 63;
    if (wid >= E) return;
    int r = ei[wid];
    int c = ei[E + wid];
    float av = 0.f;
    if (lane < 8) {
        float a = al[r * 8 + lane] + ar[c * 8 + lane];
        a  = (a >= 0.f) ? a : 0.2f * a;
        av = __expf(a) * pos[c];
    }
    float alpha = __shfl(av, lane >> 3, 64);
    float2 hv = *(const float2*)&h[(size_t)c * 128 + lane * 2];
    float* dst = &accum[(size_t)r * 128 + lane * 2];
    unsafeAtomicAdd(dst,     alpha * hv.x);
    unsafeAtomicAdd(dst + 1, alpha * hv.y);
}

// ---------------------------------------------------------------------------
// K4: out = fp32: accum * (1/rowsum + 1e-16), float4 per thread
// ---------------------------------------------------------------------------
__global__ __launch_bounds__(256) void finalize(
        const float* __restrict__ accum, const float* __restrict__ rowsum,
        float* __restrict__ out, int total4) {
    int i = blockIdx.x * 256 + threadIdx.x;
    if (i >= total4) return;
    int nn = i >> 5;
    int cq = i & 31;                 // cols cq*4..cq*4+3, head = cq>>2
    float rs = rowsum[nn * 8 + (cq >> 2)];
    float sc = (rs != 0.f) ? (1.f / rs + 1e-16f) : 0.f;
    float4 v = *(const float4*)&accum[(size_t)i * 4];
    float4 o = make_float4(v.x * sc, v.y * sc, v.z * sc, v.w * sc);
    *(float4*)&out[(size_t)i * 4] = o;
}

extern "C" void kernel_launch(void* const* d_in, const int* in_sizes, int n_in,
                              void* d_out, int out_size, void* d_ws, size_t ws_size,
                              hipStream_t stream) {
    // Identify inputs by their (unique) sizes — robust to ordering:
    // x = out_size (12.8M), pos = out_size/128 (100k), W = 16384, att = 256,
    // edge_index = the remaining one (2E = 3.2M, int32).
    const float* x   = nullptr;
    const int*   ei  = nullptr;
    const float* pos = nullptr;
    const float* W   = nullptr;
    const float* att = nullptr;
    int E2 = 0;
    for (int i = 0; i < n_in; ++i) {
        int s = in_sizes[i];
        if      (s == out_size)        x   = (const float*)d_in[i];
        else if (s == out_size / 128)  pos = (const float*)d_in[i];
        else if (s == 16384)           W   = (const float*)d_in[i];
        else if (s == 256)             att = (const float*)d_in[i];
        else { ei = (const int*)d_in[i]; E2 = s; }
    }
    float* out = (float*)d_out;

    const int N_ = out_size / 128;     // 100000
    const int E_ = E2 / 2;             // 1600000

    // workspace (floats): h[N*128] | al[N*8] | ar[N*8] | rowsum[N*8] | accum[N*128]
    float* ws_f   = (float*)d_ws;
    float* h      = ws_f;
    float* al     = h + (size_t)N_ * 128;
    float* ar     = al + (size_t)N_ * 8;
    float* rowsum = ar + (size_t)N_ * 8;
    float* accum  = rowsum + (size_t)N_ * 8;

    // zero rowsum + accum (contiguous region)
    hipMemsetAsync(rowsum, 0, ((size_t)N_ * 8 + (size_t)N_ * 128) * sizeof(float), stream);

    node_h<<<(N_ + 7) / 8, 128, 0, stream>>>(x, W, att, h, al, ar, N_);
    edge_rowsum<<<(E_ + 255) / 256, 256, 0, stream>>>(ei, pos, al, ar, rowsum, E_);
    edge_scatter<<<(E_ + 3) / 4, 256, 0, stream>>>(ei, pos, al, ar, h, accum, E_);
    finalize<<<(N_ * 32 + 255) / 256, 256, 0, stream>>>(accum, rowsum, out, N_ * 32);
}

// Round 6
// 624.366 us; speedup vs baseline: 3.5455x; 3.5455x over previous
//
#include <hip/hip_runtime.h>

// ---------------------------------------------------------------------------
// Workspace layout (see kernel_launch): h | al | ar | WT || deg | rowstart |
// cursor | bsum | csr
// Pipeline: transpose_w, node_h, hist, scan x3, fill, row_gather.
// ---------------------------------------------------------------------------

// ---- WT[k*128+c] = W[c*128+k] (once, 16384 elems) -------------------------
__global__ __launch_bounds__(256) void transpose_w(
        const float* __restrict__ W, float* __restrict__ WT) {
    int i = blockIdx.x * 256 + threadIdx.x;
    if (i < 16384) {
        int c = i >> 7, k = i & 127;
        WT[k * 128 + c] = W[i];
    }
}

// ---- h = x @ W^T, fused al/ar. 32 nodes/block, 256 thr, 16-node reg tile --
__global__ __launch_bounds__(256) void node_h(
        const float* __restrict__ x, const float* __restrict__ WT,
        const float* __restrict__ att,
        float* __restrict__ h, float* __restrict__ al, float* __restrict__ ar,
        int n) {
    __shared__ float xs[32][128];                 // 16 KB
    const int t  = threadIdx.x;
    const int nb = blockIdx.x * 32;

    for (int i = t; i < 32 * 128; i += 256) {
        int node = nb + (i >> 7);
        xs[i >> 7][i & 127] = (node < n) ? x[(size_t)node * 128 + (i & 127)] : 0.f;
    }
    __syncthreads();

    const int c    = t & 127;                     // column
    const int half = t >> 7;                      // node range half*16..+15

    float acc[16];
#pragma unroll
    for (int i = 0; i < 16; ++i) acc[i] = 0.f;

#pragma unroll 4
    for (int k = 0; k < 128; ++k) {
        float w = WT[k * 128 + c];                // coalesced across lanes
#pragma unroll
        for (int i = 0; i < 16; ++i)
            acc[i] = fmaf(xs[half * 16 + i][k], w, acc[i]);   // LDS broadcast
    }

#pragma unroll
    for (int i = 0; i < 16; ++i) {
        int node = nb + half * 16 + i;
        if (node < n) h[(size_t)node * 128 + c] = acc[i];
    }

    // al/ar: head = c>>4, d = c&15; 16-lane xor-shuffle reduction per node
    const int head = c >> 4;
    const int d    = c & 15;
    const float atl = att[head * 32 + d];
    const float atr = att[head * 32 + 16 + d];
#pragma unroll
    for (int i = 0; i < 16; ++i) {
        float pl = acc[i] * atl;
        float pr = acc[i] * atr;
#pragma unroll
        for (int off = 1; off < 16; off <<= 1) {
            pl += __shfl_xor(pl, off, 64);
            pr += __shfl_xor(pr, off, 64);
        }
        int node = nb + half * 16 + i;
        if (d == 0 && node < n) {
            al[node * 8 + head] = pl;
            ar[node * 8 + head] = pr;
        }
    }
}

// ---- degree histogram -----------------------------------------------------
__global__ __launch_bounds__(256) void edge_hist(
        const int* __restrict__ ei, int* __restrict__ deg, int E) {
    int e = blockIdx.x * 256 + threadIdx.x;
    if (e < E) atomicAdd(&deg[ei[e]], 1);
}

// ---- exclusive scan, 1024 elems/block (4/thread + 256-wide LDS scan) ------
__global__ __launch_bounds__(256) void scan_blocks(
        const int* __restrict__ deg, int* __restrict__ rowstart,
        int* __restrict__ bsum, int n) {
    __shared__ int s[256];
    int t = threadIdx.x;
    int base = blockIdx.x * 1024 + t * 4;
    int v0 = (base + 0 < n) ? deg[base + 0] : 0;
    int v1 = (base + 1 < n) ? deg[base + 1] : 0;
    int v2 = (base + 2 < n) ? deg[base + 2] : 0;
    int v3 = (base + 3 < n) ? deg[base + 3] : 0;
    int sum = v0 + v1 + v2 + v3;
    s[t] = sum;
    __syncthreads();
    for (int off = 1; off < 256; off <<= 1) {
        int tmp = (t >= off) ? s[t - off] : 0;
        __syncthreads();
        s[t] += tmp;
        __syncthreads();
    }
    int excl = s[t] - sum;
    if (base + 0 < n) rowstart[base + 0] = excl;
    if (base + 1 < n) rowstart[base + 1] = excl + v0;
    if (base + 2 < n) rowstart[base + 2] = excl + v0 + v1;
    if (base + 3 < n) rowstart[base + 3] = excl + v0 + v1 + v2;
    if (t == 255) bsum[blockIdx.x] = s[255];
}

__global__ __launch_bounds__(256) void scan_top(int* __restrict__ bsum, int nb) {
    __shared__ int s[256];
    int t = threadIdx.x;
    int v = (t < nb) ? bsum[t] : 0;
    s[t] = v;
    __syncthreads();
    for (int off = 1; off < 256; off <<= 1) {
        int tmp = (t >= off) ? s[t - off] : 0;
        __syncthreads();
        s[t] += tmp;
        __syncthreads();
    }
    if (t < nb) bsum[t] = s[t] - v;               // exclusive
}

__global__ __launch_bounds__(256) void scan_add(
        int* __restrict__ rowstart, int* __restrict__ cursor,
        const int* __restrict__ bsum, int n) {
    int i = blockIdx.x * 256 + threadIdx.x;
    if (i < n) {
        int v = rowstart[i] + bsum[i >> 10];
        rowstart[i] = v;
        cursor[i]   = v;
    }
}

// ---- fill CSR col list (cursor ends at row end) ---------------------------
__global__ __launch_bounds__(256) void edge_fill(
        const int* __restrict__ ei, int* __restrict__ cursor,
        int* __restrict__ csr, int E) {
    int e = blockIdx.x * 256 + threadIdx.x;
    if (e >= E) return;
    int r = ei[e];
    int c = ei[E + e];
    int p = atomicAdd(&cursor[r], 1);
    csr[p] = c;
}

// ---- wave per row: gather neighbors, online rowsum, normalize, store ------
__global__ __launch_bounds__(256) void row_gather(
        const int* __restrict__ csr, const int* __restrict__ rowstart,
        const int* __restrict__ rowend,
        const float* __restrict__ pos, const float* __restrict__ al,
        const float* __restrict__ ar, const float* __restrict__ h,
        float* __restrict__ out, int n) {
    int r    = (blockIdx.x * 256 + threadIdx.x) >> 6;
    int lane = threadIdx.x & 63;
    if (r >= n) return;
    int s = rowstart[r];
    int e = rowend[r];
    float al_l = (lane < 8) ? al[r * 8 + lane] : 0.f;
    float acc0 = 0.f, acc1 = 0.f, rs = 0.f;
    for (int j = s; j < e; ++j) {
        int c = csr[j];
        float av = 0.f;
        if (lane < 8) {
            float a = al_l + ar[c * 8 + lane];
            a  = (a >= 0.f) ? a : 0.2f * a;
            av = __expf(a) * pos[c];
            rs += av;
        }
        float alpha = __shfl(av, lane >> 3, 64);
        float2 hv = *(const float2*)&h[(size_t)c * 128 + lane * 2];
        acc0 = fmaf(alpha, hv.x, acc0);
        acc1 = fmaf(alpha, hv.y, acc1);
    }
    float rsh = __shfl(rs, lane >> 3, 64);
    float sc = (rsh != 0.f) ? (1.f / rsh + 1e-16f) : 0.f;
    *(float2*)&out[(size_t)r * 128 + 2 * lane] = make_float2(acc0 * sc, acc1 * sc);
}

extern "C" void kernel_launch(void* const* d_in, const int* in_sizes, int n_in,
                              void* d_out, int out_size, void* d_ws, size_t ws_size,
                              hipStream_t stream) {
    // identify inputs by unique sizes (robust to ordering)
    const float* x   = nullptr;
    const int*   ei  = nullptr;
    const float* pos = nullptr;
    const float* W   = nullptr;
    const float* att = nullptr;
    int E2 = 0;
    for (int i = 0; i < n_in; ++i) {
        int s = in_sizes[i];
        if      (s == out_size)        x   = (const float*)d_in[i];
        else if (s == out_size / 128)  pos = (const float*)d_in[i];
        else if (s == 16384)           W   = (const float*)d_in[i];
        else if (s == 256)             att = (const float*)d_in[i];
        else { ei = (const int*)d_in[i]; E2 = s; }
    }
    float* out = (float*)d_out;
    const int N_ = out_size / 128;     // 100000
    const int E_ = E2 / 2;             // 1600000

    // workspace
    float* h   = (float*)d_ws;
    float* al  = h  + (size_t)N_ * 128;
    float* ar  = al + (size_t)N_ * 8;
    float* WT  = ar + (size_t)N_ * 8;
    int* deg      = (int*)(WT + 16384);
    int* rowstart = deg + N_;
    int* cursor   = rowstart + N_;
    int* bsum     = cursor + N_;
    int* csr      = bsum + 256;

    const int nb_scan = (N_ + 1023) / 1024;      // 98 for N=100k (<=256)

    hipMemsetAsync(deg, 0, (size_t)N_ * sizeof(int), stream);

    transpose_w<<<64, 256, 0, stream>>>(W, WT);
    node_h<<<(N_ + 31) / 32, 256, 0, stream>>>(x, WT, att, h, al, ar, N_);
    edge_hist<<<(E_ + 255) / 256, 256, 0, stream>>>(ei, deg, E_);
    scan_blocks<<<nb_scan, 256, 0, stream>>>(deg, rowstart, bsum, N_);
    scan_top<<<1, 256, 0, stream>>>(bsum, nb_scan);
    scan_add<<<(N_ + 255) / 256, 256, 0, stream>>>(rowstart, cursor, bsum, N_);
    edge_fill<<<(E_ + 255) / 256, 256, 0, stream>>>(ei, cursor, csr, E_);
    row_gather<<<(N_ * 64 + 255) / 256, 256, 0, stream>>>(
        csr, rowstart, cursor, pos, al, ar, h, out, N_);
}

// Round 7
// 544.162 us; speedup vs baseline: 4.0680x; 1.1474x over previous
//
#include <hip/hip_runtime.h>

// ---------------------------------------------------------------------------
// Pipeline: transpose_w, node_h (h, al, ar), CSR build (hist/scan/fill),
// row_gather (2 edges per wave-iteration, fused normalize).
// ---------------------------------------------------------------------------

// ---- WT[k*128+c] = W[c*128+k] (once, 16384 elems) -------------------------
__global__ __launch_bounds__(256) void transpose_w(
        const float* __restrict__ W, float* __restrict__ WT) {
    int i = blockIdx.x * 256 + threadIdx.x;
    if (i < 16384) {
        int c = i >> 7, k = i & 127;
        WT[k * 128 + c] = W[i];
    }
}

// ---- h = x @ W^T, fused al/ar. 32 nodes/block, 256 thr, 16-node reg tile --
__global__ __launch_bounds__(256) void node_h(
        const float* __restrict__ x, const float* __restrict__ WT,
        const float* __restrict__ att,
        float* __restrict__ h, float* __restrict__ al, float* __restrict__ ar,
        int n) {
    __shared__ float xs[32][128];                 // 16 KB
    const int t  = threadIdx.x;
    const int nb = blockIdx.x * 32;

    for (int i = t; i < 32 * 128; i += 256) {
        int node = nb + (i >> 7);
        xs[i >> 7][i & 127] = (node < n) ? x[(size_t)node * 128 + (i & 127)] : 0.f;
    }
    __syncthreads();

    const int c    = t & 127;                     // column
    const int half = t >> 7;                      // node range half*16..+15

    float acc[16];
#pragma unroll
    for (int i = 0; i < 16; ++i) acc[i] = 0.f;

#pragma unroll 4
    for (int k = 0; k < 128; ++k) {
        float w = WT[k * 128 + c];                // coalesced across lanes
#pragma unroll
        for (int i = 0; i < 16; ++i)
            acc[i] = fmaf(xs[half * 16 + i][k], w, acc[i]);   // LDS broadcast
    }

#pragma unroll
    for (int i = 0; i < 16; ++i) {
        int node = nb + half * 16 + i;
        if (node < n) h[(size_t)node * 128 + c] = acc[i];
    }

    const int head = c >> 4;
    const int d    = c & 15;
    const float atl = att[head * 32 + d];
    const float atr = att[head * 32 + 16 + d];
#pragma unroll
    for (int i = 0; i < 16; ++i) {
        float pl = acc[i] * atl;
        float pr = acc[i] * atr;
#pragma unroll
        for (int off = 1; off < 16; off <<= 1) {
            pl += __shfl_xor(pl, off, 64);
            pr += __shfl_xor(pr, off, 64);
        }
        int node = nb + half * 16 + i;
        if (d == 0 && node < n) {
            al[node * 8 + head] = pl;
            ar[node * 8 + head] = pr;
        }
    }
}

// ---- degree histogram -----------------------------------------------------
__global__ __launch_bounds__(256) void edge_hist(
        const int* __restrict__ ei, int* __restrict__ deg, int E) {
    int e = blockIdx.x * 256 + threadIdx.x;
    if (e < E) atomicAdd(&deg[ei[e]], 1);
}

// ---- exclusive scan, 1024 elems/block -------------------------------------
__global__ __launch_bounds__(256) void scan_blocks(
        const int* __restrict__ deg, int* __restrict__ rowstart,
        int* __restrict__ bsum, int n) {
    __shared__ int s[256];
    int t = threadIdx.x;
    int base = blockIdx.x * 1024 + t * 4;
    int v0 = (base + 0 < n) ? deg[base + 0] : 0;
    int v1 = (base + 1 < n) ? deg[base + 1] : 0;
    int v2 = (base + 2 < n) ? deg[base + 2] : 0;
    int v3 = (base + 3 < n) ? deg[base + 3] : 0;
    int sum = v0 + v1 + v2 + v3;
    s[t] = sum;
    __syncthreads();
    for (int off = 1; off < 256; off <<= 1) {
        int tmp = (t >= off) ? s[t - off] : 0;
        __syncthreads();
        s[t] += tmp;
        __syncthreads();
    }
    int excl = s[t] - sum;
    if (base + 0 < n) rowstart[base + 0] = excl;
    if (base + 1 < n) rowstart[base + 1] = excl + v0;
    if (base + 2 < n) rowstart[base + 2] = excl + v0 + v1;
    if (base + 3 < n) rowstart[base + 3] = excl + v0 + v1 + v2;
    if (t == 255) bsum[blockIdx.x] = s[255];
}

__global__ __launch_bounds__(256) void scan_top(int* __restrict__ bsum, int nb) {
    __shared__ int s[256];
    int t = threadIdx.x;
    int v = (t < nb) ? bsum[t] : 0;
    s[t] = v;
    __syncthreads();
    for (int off = 1; off < 256; off <<= 1) {
        int tmp = (t >= off) ? s[t - off] : 0;
        __syncthreads();
        s[t] += tmp;
        __syncthreads();
    }
    if (t < nb) bsum[t] = s[t] - v;               // exclusive
}

__global__ __launch_bounds__(256) void scan_add(
        int* __restrict__ rowstart, int* __restrict__ cursor,
        const int* __restrict__ bsum, int n) {
    int i = blockIdx.x * 256 + threadIdx.x;
    if (i < n) {
        int v = rowstart[i] + bsum[i >> 10];
        rowstart[i] = v;
        cursor[i]   = v;
    }
}

// ---- fill CSR col list (cursor ends at row end) ---------------------------
__global__ __launch_bounds__(256) void edge_fill(
        const int* __restrict__ ei, int* __restrict__ cursor,
        int* __restrict__ csr, int E) {
    int e = blockIdx.x * 256 + threadIdx.x;
    if (e >= E) return;
    int r = ei[e];
    int c = ei[E + e];
    int p = atomicAdd(&cursor[r], 1);
    csr[p] = c;
}

// ---- wave per row, 2 edges per iteration ----------------------------------
// lanes 0-31: edge j (lane l -> cols 4l..4l+3, float4); lanes 32-63: edge j+1.
// alphas on lanes 0-7 / 32-39; halves merged by shfl_xor(32) at row end.
__global__ __launch_bounds__(256) void row_gather(
        const int* __restrict__ csr, const int* __restrict__ rowstart,
        const int* __restrict__ rowend,
        const float* __restrict__ pos, const float* __restrict__ al,
        const float* __restrict__ ar, const float* __restrict__ h,
        float* __restrict__ out, int n) {
    int r    = (blockIdx.x * 256 + threadIdx.x) >> 6;
    int lane = threadIdx.x & 63;
    if (r >= n) return;
    int s = rowstart[r];
    int e = rowend[r];
    if (s >= e) {                       // empty row -> zeros
        if (lane < 32) *(float4*)&out[(size_t)r * 128 + lane * 4] =
            make_float4(0.f, 0.f, 0.f, 0.f);
        return;
    }
    const int sub  = lane >> 5;         // which edge of the pair
    const int l31  = lane & 31;
    const int head = l31 >> 2;          // head for this lane's 4 cols
    float al_l = (l31 < 8) ? al[r * 8 + l31] : 0.f;
    float4 acc = make_float4(0.f, 0.f, 0.f, 0.f);
    float rs = 0.f;
#pragma unroll 2
    for (int j = s; j < e; j += 2) {
        int  jj    = j + sub;
        bool valid = (jj < e);
        int  c     = csr[valid ? jj : s];
        float av = 0.f;
        if (l31 < 8 && valid) {
            float a = al_l + ar[c * 8 + l31];
            a  = (a >= 0.f) ? a : 0.2f * a;
            av = __expf(a) * pos[c];
            rs += av;
        }
        float alpha = __shfl(av, (lane & 32) + head, 64);
        float4 hv = *(const float4*)&h[(size_t)c * 128 + l31 * 4];
        acc.x = fmaf(alpha, hv.x, acc.x);
        acc.y = fmaf(alpha, hv.y, acc.y);
        acc.z = fmaf(alpha, hv.z, acc.z);
        acc.w = fmaf(alpha, hv.w, acc.w);
    }
    // merge the two half-wave partial sums
    rs    += __shfl_xor(rs, 32, 64);
    acc.x += __shfl_xor(acc.x, 32, 64);
    acc.y += __shfl_xor(acc.y, 32, 64);
    acc.z += __shfl_xor(acc.z, 32, 64);
    acc.w += __shfl_xor(acc.w, 32, 64);
    float rsh = __shfl(rs, head, 64);   // total rowsum for this head
    float sc = (rsh != 0.f) ? (1.f / rsh + 1e-16f) : 0.f;
    if (lane < 32) {
        float4 o = make_float4(acc.x * sc, acc.y * sc, acc.z * sc, acc.w * sc);
        *(float4*)&out[(size_t)r * 128 + lane * 4] = o;
    }
}

extern "C" void kernel_launch(void* const* d_in, const int* in_sizes, int n_in,
                              void* d_out, int out_size, void* d_ws, size_t ws_size,
                              hipStream_t stream) {
    // identify inputs by unique sizes (robust to ordering)
    const float* x   = nullptr;
    const int*   ei  = nullptr;
    const float* pos = nullptr;
    const float* W   = nullptr;
    const float* att = nullptr;
    int E2 = 0;
    for (int i = 0; i < n_in; ++i) {
        int s = in_sizes[i];
        if      (s == out_size)        x   = (const float*)d_in[i];
        else if (s == out_size / 128)  pos = (const float*)d_in[i];
        else if (s == 16384)           W   = (const float*)d_in[i];
        else if (s == 256)             att = (const float*)d_in[i];
        else { ei = (const int*)d_in[i]; E2 = s; }
    }
    float* out = (float*)d_out;
    const int N_ = out_size / 128;     // 100000
    const int E_ = E2 / 2;             // 1600000

    // workspace
    float* h   = (float*)d_ws;
    float* al  = h  + (size_t)N_ * 128;
    float* ar  = al + (size_t)N_ * 8;
    float* WT  = ar + (size_t)N_ * 8;
    int* deg      = (int*)(WT + 16384);
    int* rowstart = deg + N_;
    int* cursor   = rowstart + N_;
    int* bsum     = cursor + N_;
    int* csr      = bsum + 256;

    const int nb_scan = (N_ + 1023) / 1024;      // <=256

    hipMemsetAsync(deg, 0, (size_t)N_ * sizeof(int), stream);

    transpose_w<<<64, 256, 0, stream>>>(W, WT);
    node_h<<<(N_ + 31) / 32, 256, 0, stream>>>(x, WT, att, h, al, ar, N_);
    edge_hist<<<(E_ + 255) / 256, 256, 0, stream>>>(ei, deg, E_);
    scan_blocks<<<nb_scan, 256, 0, stream>>>(deg, rowstart, bsum, N_);
    scan_top<<<1, 256, 0, stream>>>(bsum, nb_scan);
    scan_add<<<(N_ + 255) / 256, 256, 0, stream>>>(rowstart, cursor, bsum, N_);
    edge_fill<<<(E_ + 255) / 256, 256, 0, stream>>>(ei, cursor, csr, E_);
    row_gather<<<(N_ * 64 + 255) / 256, 256, 0, stream>>>(
        csr, rowstart, cursor, pos, al, ar, h, out, N_);
}